// Round 5
// baseline (192.127 us; speedup 1.0000x reference)
//
#include <hip/hip_runtime.h>
#include <math.h>

#define C_DIM 256
#define N_DIM 4096
#define B_DIM 8

typedef __attribute__((ext_vector_type(8))) short bf16x8;
typedef __attribute__((ext_vector_type(4))) float f32x4;
typedef __attribute__((ext_vector_type(8))) unsigned short us8;
typedef __attribute__((ext_vector_type(4))) unsigned short us4;

__device__ inline unsigned short f2bf(float f) {
    unsigned int u = __float_as_uint(f);
    u += 0x7fffu + ((u >> 16) & 1u);       // round-to-nearest-even
    return (unsigned short)(u >> 16);
}

__device__ inline void gload_lds16(const void* g, void* l) {
    __builtin_amdgcn_global_load_lds(
        (const __attribute__((address_space(1))) unsigned int*)g,
        (__attribute__((address_space(3))) unsigned int*)l, 16, 0, 0);
}

// ---------------- prep: weight cvt + bias concat + gn per-channel stats ----------------
// wq/wk/wv are written in the qkv_ws LDS image layout:
//   [ch(2)][o_local(128)][swizzled 256 K], chunk c (8 shorts) stored at
//   c' = (c&~7)|((c^o)&7)  -- so a LINEAR 64KB copy into LDS yields
//   bank-conflict-free ds_read_b128 fragments. wo stays linear (old gemm path).
__global__ __launch_bounds__(256) void prep_kernel(
    const float* __restrict__ wq, const float* __restrict__ wk,
    const float* __restrict__ wv, const float* __restrict__ wo,
    const float* __restrict__ bk, const float* __restrict__ bv,
    const float* __restrict__ x,
    unsigned short* __restrict__ wqs, unsigned short* __restrict__ wks,
    unsigned short* __restrict__ wvs, unsigned short* __restrict__ wob,
    float* __restrict__ bkv, float2* __restrict__ sums)
{
    int z = blockIdx.x;
    int t = threadIdx.x;
    if (z < 256) {
        int which = z >> 6;
        const float* s = which == 0 ? wq : which == 1 ? wk : which == 2 ? wv : wo;
        unsigned short* d = which == 0 ? wqs : which == 1 ? wks : which == 2 ? wvs : wob;
        int idx = (z & 63) * 1024 + t * 4;
        float4 v = *(const float4*)(s + idx);
        us4 r; r[0] = f2bf(v.x); r[1] = f2bf(v.y); r[2] = f2bf(v.z); r[3] = f2bf(v.w);
        int dst;
        if (which == 3) {
            dst = idx;
        } else {
            int o = idx >> 8, k = idx & 255;
            int ch = o >> 7, ol = o & 127;
            int c  = k >> 3;
            int cs = (c & ~7) | ((c ^ o) & 7);
            dst = ch * 32768 + ol * 256 + cs * 8 + (k & 7);
        }
        *(us4*)(d + dst) = r;
    } else if (z == 256) {
        bkv[t]       = bk[t];
        bkv[t + 256] = bv[t];
    } else {
        int bc = z - 257;
        const float* xc = x + (size_t)bc * N_DIM;
        float s = 0.f, q = 0.f;
        for (int i = t; i < 1024; i += 256) {
            float4 v = ((const float4*)xc)[i];
            s += v.x + v.y + v.z + v.w;
            q += v.x*v.x + v.y*v.y + v.z*v.z + v.w*v.w;
        }
        #pragma unroll
        for (int off = 32; off > 0; off >>= 1) {
            s += __shfl_down(s, off);
            q += __shfl_down(q, off);
        }
        __shared__ float red[8];
        int w = t >> 6;
        if ((t & 63) == 0) { red[w*2] = s; red[w*2+1] = q; }
        __syncthreads();
        if (t == 0) {
            sums[bc] = make_float2(red[0]+red[2]+red[4]+red[6],
                                   red[1]+red[3]+red[5]+red[7]);
        }
    }
}

// ---------------- GroupNorm apply + transpose -> bf16 hT[b][n][c] ----------------
__global__ __launch_bounds__(256) void gn_apply(const float* __restrict__ x,
                                                const float2* __restrict__ sums,
                                                const float* __restrict__ gamma,
                                                const float* __restrict__ beta,
                                                unsigned short* __restrict__ hT) {
    int b = blockIdx.y, n0 = blockIdx.x * 64;
    int t = threadIdx.x;
    __shared__ float scale[256], shift[256];
    __shared__ unsigned short trans[64][264];

    {
        int c = t;
        int gbase = c & ~7;
        float s = 0.f, q = 0.f;
        #pragma unroll
        for (int j = 0; j < 8; j++) {
            float2 u = sums[b*256 + gbase + j];
            s += u.x; q += u.y;
        }
        float mean = s * (1.f/32768.f);
        float var  = q * (1.f/32768.f) - mean*mean;
        float inv  = rsqrtf(var + 1e-6f);
        float gm = gamma[c] * inv;
        scale[c] = gm;
        shift[c] = beta[c] - mean * gm;
    }
    __syncthreads();

    #pragma unroll
    for (int it = 0; it < 16; it++) {
        int c  = it*16 + (t >> 4);
        int nl = (t & 15) * 4;
        float4 v = *(const float4*)(x + ((size_t)(b*C_DIM + c))*N_DIM + n0 + nl);
        float sc = scale[c], sh = shift[c];
        trans[nl+0][c] = f2bf(v.x*sc + sh);
        trans[nl+1][c] = f2bf(v.y*sc + sh);
        trans[nl+2][c] = f2bf(v.z*sc + sh);
        trans[nl+3][c] = f2bf(v.w*sc + sh);
    }
    __syncthreads();

    #pragma unroll
    for (int it = 0; it < 8; it++) {
        int nl = it*8 + (t >> 5);
        int cb = (t & 31) * 8;
        us8 vv = *(us8*)&trans[nl][cb];
        *(us8*)(hT + ((size_t)b*N_DIM + n0 + nl)*C_DIM + cb) = vv;
    }
}

// ---------------- kv split-K reduce + cvt (16 splits) ----------------
__global__ __launch_bounds__(256) void kvred(const float* __restrict__ src, unsigned short* __restrict__ dst) {
    int gi = (blockIdx.x * 256 + threadIdx.x) * 4;
    int b = gi >> 16, idx = gi & 65535;
    float4 a = make_float4(0.f,0.f,0.f,0.f);
    #pragma unroll
    for (int sp = 0; sp < 16; sp++) {
        float4 v = *(const float4*)(src + (((size_t)b*16 + sp) << 16) + idx);
        a.x += v.x; a.y += v.y; a.z += v.z; a.w += v.w;
    }
    us4 r; r[0] = f2bf(a.x); r[1] = f2bf(a.y); r[2] = f2bf(a.z); r[3] = f2bf(a.w);
    *(us4*)(dst + ((size_t)b << 16) + idx) = r;
}

// ================= qkv_ws: persistent-weight, barrier-free tall-skinny GEMM ==========
// roles: 0=Q  qT[g][o]   = elu1(hT[g][:]*wq[o][:] + bq[o])
//        1=K  kvbuf[b][cc][n]      = elu1(hT*wk + bk)
//        2=V  kvbuf[b][256+cc][n]  =       hT*wv + bv
// grid z = role*512 + chunk*2 + ch : 256 row-chunks of 128 rows, 2 col-halves of 128.
// Block: 256 thr = 4 waves (2 row-grp x 2 col-grp of 64), 64KB resident weights.
// Prologue: ONE linear global_load_lds of the pre-swizzled weight image + 1 barrier.
// Main loop: NO barriers; per step 4 a-frags direct global->reg (depth-2 prefetch),
// 4 swizzled ds_read_b128 b-frags, 16 MFMA.
__global__ __launch_bounds__(256) void qkv_ws(
    const unsigned short* __restrict__ hT,
    const unsigned short* __restrict__ wqs, const unsigned short* __restrict__ wks,
    const unsigned short* __restrict__ wvs,
    const float* __restrict__ bq, const float* __restrict__ bkv,
    unsigned short* __restrict__ qT, unsigned short* __restrict__ kvbuf)
{
    __shared__ __align__(16) unsigned short W[32768];   // 64 KB
    int z = blockIdx.x;
    int role    = z >> 9;
    int chunk   = (z >> 1) & 255;
    int ch      = z & 1;
    int rowbase = chunk * 128;
    int colbase = ch * 128;
    int t = threadIdx.x;

    const unsigned short* wsrc = (role == 0 ? wqs : role == 1 ? wks : wvs) + ch * 32768;

    #pragma unroll
    for (int it = 0; it < 16; ++it)
        gload_lds16(wsrc + (it*256 + t)*8, W + (it*256 + t)*8);

    int w = t >> 6, l = t & 63;
    int wr = w >> 1, wc = w & 1;
    int l15 = l & 15, quad = l >> 4;
    int x7 = l15 & 7;

    const float* bsrc = role == 0 ? bq : bkv + (role == 2 ? 256 : 0);
    float bias[4];
    #pragma unroll
    for (int j = 0; j < 4; ++j) bias[j] = bsrc[colbase + wc*64 + j*16 + l15];

    const unsigned short* aB[4];
    #pragma unroll
    for (int i = 0; i < 4; ++i)
        aB[i] = hT + (size_t)(rowbase + wr*64 + i*16 + l15) * 256 + quad*8;

    asm volatile("s_waitcnt vmcnt(0)" ::: "memory");
    __syncthreads();

    // depth-2 register prefetch of A fragments
    bf16x8 A[3][4];
    #pragma unroll
    for (int i = 0; i < 4; ++i) A[0][i] = *(const bf16x8*)(aB[i]);
    #pragma unroll
    for (int i = 0; i < 4; ++i) A[1][i] = *(const bf16x8*)(aB[i] + 32);

    f32x4 acc[4][4];
    #pragma unroll
    for (int i = 0; i < 4; ++i)
        #pragma unroll
        for (int j = 0; j < 4; ++j)
            #pragma unroll
            for (int r = 0; r < 4; ++r) acc[i][j][r] = 0.f;

    #pragma unroll
    for (int s = 0; s < 8; ++s) {
        // b-frags: chunk c = s*4+quad, stored at c' = (c&~7)|((c&7)^x7)
        int coff = ((s >> 1)*8 + ((quad + 4*(s & 1)) ^ x7)) * 8;
        bf16x8 bfr[4];
        #pragma unroll
        for (int j = 0; j < 4; ++j)
            bfr[j] = *(const bf16x8*)(W + (wc*64 + j*16 + l15)*256 + coff);
        if (s + 2 < 8) {
            #pragma unroll
            for (int i = 0; i < 4; ++i)
                A[(s + 2) % 3][i] = *(const bf16x8*)(aB[i] + (s + 2)*32);
        }
        #pragma unroll
        for (int i = 0; i < 4; ++i)
            #pragma unroll
            for (int j = 0; j < 4; ++j)
                acc[i][j] = __builtin_amdgcn_mfma_f32_16x16x32_bf16(A[s % 3][i], bfr[j], acc[i][j], 0, 0, 0);
    }

    if (role == 0) {
        #pragma unroll
        for (int i = 0; i < 4; ++i) {
            int g = rowbase + wr*64 + i*16 + quad*4;
            #pragma unroll
            for (int j = 0; j < 4; ++j) {
                int col = colbase + wc*64 + j*16 + l15;
                #pragma unroll
                for (int r = 0; r < 4; ++r) {
                    float v = acc[i][j][r] + bias[j];
                    v = v > 0.f ? v + 1.f : __expf(v);
                    qT[(size_t)(g + r)*256 + col] = f2bf(v);
                }
            }
        }
    } else {
        int b = rowbase >> 12, n0 = rowbase & 4095;
        int ccb = (role == 2) ? 256 : 0;
        unsigned short* base = kvbuf + (size_t)b * 2097152;
        #pragma unroll
        for (int i = 0; i < 4; ++i) {
            int n = n0 + wr*64 + i*16 + quad*4;
            #pragma unroll
            for (int j = 0; j < 4; ++j) {
                int cc = ccb + colbase + wc*64 + j*16 + l15;
                us4 pk;
                #pragma unroll
                for (int r = 0; r < 4; ++r) {
                    float v = acc[i][j][r] + bias[j];
                    if (role == 1) v = v > 0.f ? v + 1.f : __expf(v);
                    pk[r] = f2bf(v);
                }
                *(us4*)(base + (size_t)cc*4096 + n) = pk;
            }
        }
    }
}

// ================= shared NT bf16 MFMA GEMM body (modes 3,4,5) =================
// 128x128 tile, BK=32, 4 waves, depth-2 counted-vmcnt pipeline, triple-buffered LDS,
// both-sides chunk swizzle (R4).
template<int MODE>
__device__ __forceinline__ void gemm_body(
    const unsigned short* __restrict__ Ab, const unsigned short* __restrict__ Bb,
    const float* __restrict__ bias, const float* __restrict__ residb,
    void* __restrict__ Cb,
    int N, int K, int k0, int Ks, int m_blk, int n_blk, bool elu,
    char* smem)
{
    unsigned short* lds = (unsigned short*)smem;

    int t = threadIdx.x;
    int w = t >> 6, l = t & 63;
    int wm = w >> 1, wn = w & 1;
    int l15 = l & 15, quad = l >> 4;

    int srow = w * 16 + (l >> 2);
    int skc  = (((l & 3) ^ ((l >> 3) & 3)) * 8);   // swizzled global column

    f32x4 acc[4][4];
    #pragma unroll
    for (int i = 0; i < 4; i++)
        #pragma unroll
        for (int j = 0; j < 4; j++)
            #pragma unroll
            for (int r = 0; r < 4; r++) acc[i][j][r] = 0.f;

    auto stage = [&](int buf, int kt) {
        unsigned short* Asl = lds + buf*8192 + t*8;
        unsigned short* Bsl = Asl + 4096;
        #pragma unroll
        for (int rep = 0; rep < 2; rep++) {
            gload_lds16(Ab + (size_t)(m_blk + rep*64 + srow) * K + kt + skc, Asl + rep*2048);
            gload_lds16(Bb + (size_t)(n_blk + rep*64 + srow) * K + kt + skc, Bsl + rep*2048);
        }
    };

    const int nt = Ks >> 5;

    stage(0, k0);
    if (nt > 1) stage(1, k0 + 32);

    int rsw = (l15 >> 1) & 3;
    int acol = (quad ^ rsw) * 8;

    int bufc = 0;
    for (int kt = 0; kt < nt; ++kt) {
        if (kt + 1 < nt) asm volatile("s_waitcnt vmcnt(4)" ::: "memory");
        else             asm volatile("s_waitcnt vmcnt(0)" ::: "memory");
        __builtin_amdgcn_s_barrier();
        __builtin_amdgcn_sched_barrier(0);
        if (kt + 2 < nt) {
            int bufn = bufc + 2; if (bufn >= 3) bufn -= 3;
            stage(bufn, k0 + (kt + 2) * 32);
        }
        __builtin_amdgcn_sched_barrier(0);

        const unsigned short* Aw = lds + bufc*8192 + (wm*64 + l15)*32 + acol;
        const unsigned short* Bw = lds + bufc*8192 + 4096 + (wn*64 + l15)*32 + acol;
        bf16x8 af[4], bfr[4];
        #pragma unroll
        for (int i = 0; i < 4; i++) af[i]  = *(const bf16x8*)(Aw + i*512);
        #pragma unroll
        for (int j = 0; j < 4; j++) bfr[j] = *(const bf16x8*)(Bw + j*512);
        __builtin_amdgcn_s_setprio(1);
        #pragma unroll
        for (int i = 0; i < 4; i++)
            #pragma unroll
            for (int j = 0; j < 4; j++)
                acc[i][j] = __builtin_amdgcn_mfma_f32_16x16x32_bf16(af[i], bfr[j], acc[i][j], 0, 0, 0);
        __builtin_amdgcn_s_setprio(0);
        bufc = (bufc == 2) ? 0 : bufc + 1;
    }
    __syncthreads();

    if (MODE == 4) {
        unsigned short* ep = (unsigned short*)smem;
        unsigned short* Cp = (unsigned short*)Cb;
        #pragma unroll
        for (int h = 0; h < 2; h++) {
            if (wm == h) {
                int row0 = quad*4;
                int col0 = wn*64 + l15;
                #pragma unroll
                for (int i = 0; i < 4; i++) {
                    #pragma unroll
                    for (int j = 0; j < 4; j++) {
                        int cl = col0 + j*16;
                        #pragma unroll
                        for (int r = 0; r < 4; r++) {
                            int rl = row0 + i*16 + r;
                            ep[rl*136 + cl] = f2bf(acc[i][j][r]);
                        }
                    }
                }
            }
            __syncthreads();
            #pragma unroll
            for (int it = 0; it < 4; it++) {
                int row = it*16 + (t >> 4);
                int col = (t & 15) * 8;
                us8 vv = *(us8*)(ep + row*136 + col);
                *(us8*)(Cp + (size_t)(m_blk + h*64 + row) * N + n_blk + col) = vv;
            }
            __syncthreads();
        }
    } else {
        float* ep32 = (float*)smem;
        float* Cp = (float*)Cb;
        #pragma unroll
        for (int h = 0; h < 2; h++) {
            if (wm == h) {
                int row0 = quad*4;
                int col0 = wn*64 + l15;
                #pragma unroll
                for (int i = 0; i < 4; i++)
                    #pragma unroll
                    for (int j = 0; j < 4; j++)
                        #pragma unroll
                        for (int r = 0; r < 4; r++)
                            ep32[(row0 + i*16 + r)*140 + col0 + j*16] = acc[i][j][r];
            }
            __syncthreads();
            #pragma unroll
            for (int it = 0; it < 8; it++) {
                int rl  = it*8 + (t >> 5);
                int row = m_blk + h*64 + rl;
                int col = (t & 31) * 4;
                f32x4 vv = *(f32x4*)(ep32 + rl*140 + col);
                if (MODE == 5) {
                    float bi = bias[row];
                    float4 rv = *(const float4*)(residb + (size_t)row * N + n_blk + col);
                    vv[0] += bi + rv.x; vv[1] += bi + rv.y;
                    vv[2] += bi + rv.z; vv[3] += bi + rv.w;
                }
                *(f32x4*)(Cp + (size_t)row * N + n_blk + col) = vv;
            }
            __syncthreads();
        }
    }
}

template<int MODE>
__global__ __launch_bounds__(256) void gemm_nt(
    const unsigned short* __restrict__ A, const unsigned short* __restrict__ B,
    const float* __restrict__ bias, const float* __restrict__ resid,
    void* __restrict__ Cout,
    int N, int K, int splits,
    size_t sA, size_t sB, size_t sC, size_t sR, int elem4)
{
    __shared__ __align__(16) char smem[49152];
    int b  = blockIdx.z / splits;
    int sp = blockIdx.z % splits;
    int Ks = K / splits;
    size_t cbase = (MODE == 3) ? ((size_t)(b*splits + sp)) * sC : (size_t)b * sC;
    void* Cb = elem4 ? (void*)((float*)Cout + cbase) : (void*)((unsigned short*)Cout + cbase);
    gemm_body<MODE>(A + b*sA, B + b*sB, bias,
                    resid ? resid + b*sR : nullptr, Cb,
                    N, K, sp*Ks, Ks, blockIdx.y*128, blockIdx.x*128, false, smem);
}

extern "C" void kernel_launch(void* const* d_in, const int* in_sizes, int n_in,
                              void* d_out, int out_size, void* d_ws, size_t ws_size,
                              hipStream_t stream) {
    const float* x     = (const float*)d_in[0];
    const float* gamma = (const float*)d_in[1];
    const float* beta  = (const float*)d_in[2];
    const float* wq    = (const float*)d_in[3];
    const float* bq    = (const float*)d_in[4];
    const float* wk    = (const float*)d_in[5];
    const float* bk    = (const float*)d_in[6];
    const float* wv    = (const float*)d_in[7];
    const float* bv    = (const float*)d_in[8];
    const float* wo    = (const float*)d_in[9];
    const float* bo    = (const float*)d_in[10];
    float* out = (float*)d_out;

    const size_t TEN = (size_t)B_DIM * C_DIM * N_DIM;   // 8,388,608 elems
    unsigned short* ws16  = (unsigned short*)d_ws;
    unsigned short* hT    = ws16;                    // [B][N][C] bf16
    unsigned short* qT    = hT    + TEN;             // [B][N][C] bf16
    unsigned short* kvbuf = qT    + TEN;             // [B][512][N] bf16
    unsigned short* kvb   = kvbuf + 2*TEN;           // [B][C][C] bf16
    unsigned short* M2b   = kvb   + 524288;          // [B][C][C] bf16
    unsigned short* wqs   = M2b   + 524288;          // swizzled [2][128][256]
    unsigned short* wks   = wqs   + 65536;
    unsigned short* wvs   = wks   + 65536;
    unsigned short* wob   = wvs   + 65536;           // linear (old layout)
    float*          bkv   = (float*)(wob + 65536);   // [512]
    float2*         sums  = (float2*)(bkv + 512);    // [B*C]
    float*          kvf   = (float*)(sums + 2048);   // [B][16][C*C] fp32 partials

    // 1) prep: weights->bf16 (q/k/v swizzled), bias concat, gn stats
    prep_kernel<<<dim3(2305), 256, 0, stream>>>(wq, wk, wv, wo, bk, bv, x,
                                                wqs, wks, wvs, wob, bkv, sums);
    // 2) groupnorm apply -> hT
    gn_apply<<<dim3(N_DIM/64, B_DIM), 256, 0, stream>>>(x, sums, gamma, beta, hT);
    // 3) persistent-weight barrier-free q/k/v
    qkv_ws<<<dim3(1536), 256, 0, stream>>>(hT, wqs, wks, wvs, bq, bkv, qT, kvbuf);
    // 4) kv[c][d] = sum_n k[c][n]*v[d][n]  M=256 N=256 K=4096, split-16 fp32
    gemm_nt<3><<<dim3(2, 2, B_DIM*16), 256, 0, stream>>>(
        kvbuf, kvbuf + 1048576, nullptr, nullptr, kvf,
        256, 4096, 16, 2097152, 2097152, 65536, 0, 1);
    // 5) reduce 16 partials -> kvb bf16
    kvred<<<dim3(512), 256, 0, stream>>>(kvf, kvb);
    // 6) M2[o][c] = sum_d wo[o][d]*kv[c][d]  M=256 N=256 K=256
    gemm_nt<4><<<dim3(2, 2, B_DIM), 256, 0, stream>>>(
        wob, kvb, nullptr, nullptr, M2b,
        256, 256, 1, 0, 65536, 65536, 0, 0);
    // 7) out[o][n] = sum_c M2[o][c]*qT[n][c] + bo[o] + x  M=256 N=4096 K=256
    gemm_nt<5><<<dim3(32, 2, B_DIM), 256, 0, stream>>>(
        M2b, qT, bo, x, out,
        4096, 256, 1, 65536, 1048576, 1048576, 1048576, 1);
}

// Round 6
// 182.603 us; speedup vs baseline: 1.0522x; 1.0522x over previous
//
#include <hip/hip_runtime.h>
#include <math.h>

#define C_DIM 256
#define N_DIM 4096
#define B_DIM 8

typedef __attribute__((ext_vector_type(8))) short bf16x8;
typedef __attribute__((ext_vector_type(4))) float f32x4;
typedef __attribute__((ext_vector_type(8))) unsigned short us8;
typedef __attribute__((ext_vector_type(4))) unsigned short us4;

__device__ inline unsigned short f2bf(float f) {
    unsigned int u = __float_as_uint(f);
    u += 0x7fffu + ((u >> 16) & 1u);       // round-to-nearest-even
    return (unsigned short)(u >> 16);
}

__device__ inline void gload_lds16(const void* g, void* l) {
    __builtin_amdgcn_global_load_lds(
        (const __attribute__((address_space(1))) unsigned int*)g,
        (__attribute__((address_space(3))) unsigned int*)l, 16, 0, 0);
}

// ---------------- prep: weight cvt + bias concat + gn per-channel stats ----------------
__global__ __launch_bounds__(256) void prep_kernel(
    const float* __restrict__ wq, const float* __restrict__ wk,
    const float* __restrict__ wv, const float* __restrict__ wo,
    const float* __restrict__ bk, const float* __restrict__ bv,
    const float* __restrict__ x,
    unsigned short* __restrict__ wqb, unsigned short* __restrict__ wkvb,
    unsigned short* __restrict__ wob, float* __restrict__ bkv,
    float2* __restrict__ sums)
{
    int z = blockIdx.x;
    int t = threadIdx.x;
    if (z < 256) {
        const float* s; unsigned short* d;
        int which = z >> 6;
        if (which == 0)      { s = wq; d = wqb; }
        else if (which == 1) { s = wk; d = wkvb; }
        else if (which == 2) { s = wv; d = wkvb + 65536; }
        else                 { s = wo; d = wob; }
        int idx = (z & 63) * 1024 + t * 4;
        float4 v = *(const float4*)(s + idx);
        us4 r; r[0] = f2bf(v.x); r[1] = f2bf(v.y); r[2] = f2bf(v.z); r[3] = f2bf(v.w);
        *(us4*)(d + idx) = r;
    } else if (z == 256) {
        bkv[t]       = bk[t];
        bkv[t + 256] = bv[t];
    } else {
        int bc = z - 257;
        const float* xc = x + (size_t)bc * N_DIM;
        float s = 0.f, q = 0.f;
        for (int i = t; i < 1024; i += 256) {
            float4 v = ((const float4*)xc)[i];
            s += v.x + v.y + v.z + v.w;
            q += v.x*v.x + v.y*v.y + v.z*v.z + v.w*v.w;
        }
        #pragma unroll
        for (int off = 32; off > 0; off >>= 1) {
            s += __shfl_down(s, off);
            q += __shfl_down(q, off);
        }
        __shared__ float red[8];
        int w = t >> 6;
        if ((t & 63) == 0) { red[w*2] = s; red[w*2+1] = q; }
        __syncthreads();
        if (t == 0) {
            sums[bc] = make_float2(red[0]+red[2]+red[4]+red[6],
                                   red[1]+red[3]+red[5]+red[7]);
        }
    }
}

// ---------------- GroupNorm apply + transpose -> bf16 hT[b][n][c] ----------------
__global__ __launch_bounds__(256) void gn_apply(const float* __restrict__ x,
                                                const float2* __restrict__ sums,
                                                const float* __restrict__ gamma,
                                                const float* __restrict__ beta,
                                                unsigned short* __restrict__ hT) {
    int b = blockIdx.y, n0 = blockIdx.x * 64;
    int t = threadIdx.x;
    __shared__ float scale[256], shift[256];
    __shared__ unsigned short trans[64][264];

    {
        int c = t;
        int gbase = c & ~7;
        float s = 0.f, q = 0.f;
        #pragma unroll
        for (int j = 0; j < 8; j++) {
            float2 u = sums[b*256 + gbase + j];
            s += u.x; q += u.y;
        }
        float mean = s * (1.f/32768.f);
        float var  = q * (1.f/32768.f) - mean*mean;
        float inv  = rsqrtf(var + 1e-6f);
        float gm = gamma[c] * inv;
        scale[c] = gm;
        shift[c] = beta[c] - mean * gm;
    }
    __syncthreads();

    #pragma unroll
    for (int it = 0; it < 16; it++) {
        int c  = it*16 + (t >> 4);
        int nl = (t & 15) * 4;
        float4 v = *(const float4*)(x + ((size_t)(b*C_DIM + c))*N_DIM + n0 + nl);
        float sc = scale[c], sh = shift[c];
        trans[nl+0][c] = f2bf(v.x*sc + sh);
        trans[nl+1][c] = f2bf(v.y*sc + sh);
        trans[nl+2][c] = f2bf(v.z*sc + sh);
        trans[nl+3][c] = f2bf(v.w*sc + sh);
    }
    __syncthreads();

    #pragma unroll
    for (int it = 0; it < 8; it++) {
        int nl = it*8 + (t >> 5);
        int cb = (t & 31) * 8;
        us8 vv = *(us8*)&trans[nl][cb];
        *(us8*)(hT + ((size_t)b*N_DIM + n0 + nl)*C_DIM + cb) = vv;
    }
}

// ---------------- kv split-K reduce + cvt (8 splits) ----------------
__global__ __launch_bounds__(256) void kvred(const float* __restrict__ src, unsigned short* __restrict__ dst) {
    int gi = (blockIdx.x * 256 + threadIdx.x) * 4;
    int b = gi >> 16, idx = gi & 65535;
    float4 a = make_float4(0.f,0.f,0.f,0.f);
    #pragma unroll
    for (int sp = 0; sp < 8; sp++) {
        float4 v = *(const float4*)(src + (((size_t)b*8 + sp) << 16) + idx);
        a.x += v.x; a.y += v.y; a.z += v.z; a.w += v.w;
    }
    us4 r; r[0] = f2bf(a.x); r[1] = f2bf(a.y); r[2] = f2bf(a.z); r[3] = f2bf(a.w);
    *(us4*)(dst + ((size_t)b << 16) + idx) = r;
}

// ================= shared NT bf16 MFMA GEMM body =================
// C[m][n] = sum_k A[m][k]*B[n][k]; 128x128 tile, BK=32, 4 waves (2x2), 4x4 of 16x16x32
// Depth-2 counted-vmcnt pipeline, triple-buffered LDS (3 x 16KB = 48KB).
// Both-sides chunk swizzle (R4, verified: conflicts 1.77M -> 196K).
// MODE: 0 = bf16 out, bias[col], elu     (qT)
//       1 = bf16 out, bias[row], runtime elu (k/v stacked)
//       3 = fp32 out (split partial)     (kv)
//       4 = bf16 out, no bias            (M2)
//       5 = fp32 out, bias[row] + resid  (out)
template<int MODE>
__device__ __forceinline__ void gemm_body(
    const unsigned short* __restrict__ Ab, const unsigned short* __restrict__ Bb,
    const float* __restrict__ bias, const float* __restrict__ residb,
    void* __restrict__ Cb,
    int N, int K, int k0, int Ks, int m_blk, int n_blk, bool elu,
    char* smem)
{
    unsigned short* lds = (unsigned short*)smem;

    int t = threadIdx.x;
    int w = t >> 6, l = t & 63;
    int wm = w >> 1, wn = w & 1;
    int l15 = l & 15, quad = l >> 4;

    int srow = w * 16 + (l >> 2);
    int skc  = (((l & 3) ^ ((l >> 3) & 3)) * 8);   // swizzled global column

    f32x4 acc[4][4];
    #pragma unroll
    for (int i = 0; i < 4; i++)
        #pragma unroll
        for (int j = 0; j < 4; j++)
            #pragma unroll
            for (int r = 0; r < 4; r++) acc[i][j][r] = 0.f;

    auto stage = [&](int buf, int kt) {
        unsigned short* Asl = lds + buf*8192 + t*8;
        unsigned short* Bsl = Asl + 4096;
        #pragma unroll
        for (int rep = 0; rep < 2; rep++) {
            gload_lds16(Ab + (size_t)(m_blk + rep*64 + srow) * K + kt + skc, Asl + rep*2048);
            gload_lds16(Bb + (size_t)(n_blk + rep*64 + srow) * K + kt + skc, Bsl + rep*2048);
        }
    };

    const int nt = Ks >> 5;

    // prologue: stage tiles 0 and 1 (8 loads/thread in flight)
    stage(0, k0);
    if (nt > 1) stage(1, k0 + 32);

    int rsw = (l15 >> 1) & 3;                       // row bits 1-2 for this lane's reads
    int acol = (quad ^ rsw) * 8;                    // swizzled LDS read column (shorts)

    int bufc = 0;
    for (int kt = 0; kt < nt; ++kt) {
        // tile kt's 4 loads are the oldest; <=4 outstanding leaves only kt+1's in flight
        if (kt + 1 < nt) asm volatile("s_waitcnt vmcnt(4)" ::: "memory");
        else             asm volatile("s_waitcnt vmcnt(0)" ::: "memory");
        __builtin_amdgcn_s_barrier();
        __builtin_amdgcn_sched_barrier(0);
        if (kt + 2 < nt) {
            int bufn = bufc + 2; if (bufn >= 3) bufn -= 3;
            stage(bufn, k0 + (kt + 2) * 32);
        }
        __builtin_amdgcn_sched_barrier(0);

        const unsigned short* Aw = lds + bufc*8192 + (wm*64 + l15)*32 + acol;
        const unsigned short* Bw = lds + bufc*8192 + 4096 + (wn*64 + l15)*32 + acol;
        bf16x8 af[4], bfr[4];
        #pragma unroll
        for (int i = 0; i < 4; i++) af[i]  = *(const bf16x8*)(Aw + i*512);
        #pragma unroll
        for (int j = 0; j < 4; j++) bfr[j] = *(const bf16x8*)(Bw + j*512);
        __builtin_amdgcn_s_setprio(1);
        #pragma unroll
        for (int i = 0; i < 4; i++)
            #pragma unroll
            for (int j = 0; j < 4; j++)
                acc[i][j] = __builtin_amdgcn_mfma_f32_16x16x32_bf16(af[i], bfr[j], acc[i][j], 0, 0, 0);
        __builtin_amdgcn_s_setprio(0);
        bufc = (bufc == 2) ? 0 : bufc + 1;
    }
    __syncthreads();   // protect LDS: epilogue reuses staging buffers

    if (MODE == 0 || MODE == 1 || MODE == 4) {
        // bf16 epilogue in two 64-row half passes: 64x136 shorts = 17.4KB
        unsigned short* ep = (unsigned short*)smem;
        unsigned short* Cp = (unsigned short*)Cb;
        #pragma unroll
        for (int h = 0; h < 2; h++) {
            if (wm == h) {
                int row0 = quad*4;
                int col0 = wn*64 + l15;
                #pragma unroll
                for (int i = 0; i < 4; i++) {
                    #pragma unroll
                    for (int j = 0; j < 4; j++) {
                        int cl = col0 + j*16;
                        #pragma unroll
                        for (int r = 0; r < 4; r++) {
                            int rl = row0 + i*16 + r;
                            float val = acc[i][j][r];
                            if (MODE == 0) {
                                val += bias[n_blk + cl];
                                val = val > 0.f ? val + 1.f : __expf(val);
                            } else if (MODE == 1) {
                                val += bias[m_blk + h*64 + rl];
                                if (elu) val = val > 0.f ? val + 1.f : __expf(val);
                            }
                            ep[rl*136 + cl] = f2bf(val);
                        }
                    }
                }
            }
            __syncthreads();
            #pragma unroll
            for (int it = 0; it < 4; it++) {
                int row = it*16 + (t >> 4);
                int col = (t & 15) * 8;
                us8 vv = *(us8*)(ep + row*136 + col);
                *(us8*)(Cp + (size_t)(m_blk + h*64 + row) * N + n_blk + col) = vv;
            }
            __syncthreads();
        }
    } else {
        float* ep32 = (float*)smem;
        float* Cp = (float*)Cb;
        #pragma unroll
        for (int h = 0; h < 2; h++) {
            if (wm == h) {
                int row0 = quad*4;
                int col0 = wn*64 + l15;
                #pragma unroll
                for (int i = 0; i < 4; i++)
                    #pragma unroll
                    for (int j = 0; j < 4; j++)
                        #pragma unroll
                        for (int r = 0; r < 4; r++)
                            ep32[(row0 + i*16 + r)*140 + col0 + j*16] = acc[i][j][r];
            }
            __syncthreads();
            #pragma unroll
            for (int it = 0; it < 8; it++) {
                int rl  = it*8 + (t >> 5);
                int row = m_blk + h*64 + rl;
                int col = (t & 31) * 4;
                f32x4 vv = *(f32x4*)(ep32 + rl*140 + col);
                if (MODE == 5) {
                    float bi = bias[row];
                    float4 rv = *(const float4*)(residb + (size_t)row * N + n_blk + col);
                    vv[0] += bi + rv.x; vv[1] += bi + rv.y;
                    vv[2] += bi + rv.z; vv[3] += bi + rv.w;
                }
                *(f32x4*)(Cp + (size_t)row * N + n_blk + col) = vv;
            }
            __syncthreads();
        }
    }
}

// ---------------- fused QKV launch: z<512 -> qT, else stacked k/v ----------------
__global__ __launch_bounds__(256) void qkv_kernel(
    const unsigned short* __restrict__ hT, const unsigned short* __restrict__ wqb,
    const unsigned short* __restrict__ wkvb,
    const float* __restrict__ bq, const float* __restrict__ bkv,
    unsigned short* __restrict__ qT, unsigned short* __restrict__ kvbuf)
{
    __shared__ __align__(16) char smem[49152];   // 48KB -> 3 blocks/CU
    int z = blockIdx.x;
    if (z < 512) {
        // qT[n][o]: A=hT (M=4096), B=wq (N=256), K=256
        int b = z >> 6, rem = z & 63;
        int m_blk = (rem >> 1) * 128, n_blk = (rem & 1) * 128;
        gemm_body<0>(hT + (size_t)b*1048576, wqb, bq, nullptr,
                     qT + (size_t)b*1048576,
                     256, 256, 0, 256, m_blk, n_blk, true, smem);
    } else {
        // kvbuf[cc][n]: A=wkv (M=512), B=hT (N=4096), K=256; elu on rows<256 (k)
        int iz = z - 512;
        int b = iz >> 7, rem = iz & 127;
        int m_blk = (rem >> 5) * 128, n_blk = (rem & 31) * 128;
        gemm_body<1>(wkvb, hT + (size_t)b*1048576, bkv, nullptr,
                     kvbuf + (size_t)b*2097152,
                     4096, 256, 0, 256, m_blk, n_blk, m_blk < 256, smem);
    }
}

// ---------------- generic NT GEMM kernel for modes 3,4,5 ----------------
template<int MODE>
__global__ __launch_bounds__(256) void gemm_nt(
    const unsigned short* __restrict__ A, const unsigned short* __restrict__ B,
    const float* __restrict__ bias, const float* __restrict__ resid,
    void* __restrict__ Cout,
    int N, int K, int splits,
    size_t sA, size_t sB, size_t sC, size_t sR, int elem4)
{
    __shared__ __align__(16) char smem[49152];
    int b  = blockIdx.z / splits;
    int sp = blockIdx.z % splits;
    int Ks = K / splits;
    size_t cbase = (MODE == 3) ? ((size_t)(b*splits + sp)) * sC : (size_t)b * sC;
    void* Cb = elem4 ? (void*)((float*)Cout + cbase) : (void*)((unsigned short*)Cout + cbase);
    gemm_body<MODE>(A + b*sA, B + b*sB, bias,
                    resid ? resid + b*sR : nullptr, Cb,
                    N, K, sp*Ks, Ks, blockIdx.y*128, blockIdx.x*128, false, smem);
}

extern "C" void kernel_launch(void* const* d_in, const int* in_sizes, int n_in,
                              void* d_out, int out_size, void* d_ws, size_t ws_size,
                              hipStream_t stream) {
    const float* x     = (const float*)d_in[0];
    const float* gamma = (const float*)d_in[1];
    const float* beta  = (const float*)d_in[2];
    const float* wq    = (const float*)d_in[3];
    const float* bq    = (const float*)d_in[4];
    const float* wk    = (const float*)d_in[5];
    const float* bk    = (const float*)d_in[6];
    const float* wv    = (const float*)d_in[7];
    const float* bv    = (const float*)d_in[8];
    const float* wo    = (const float*)d_in[9];
    const float* bo    = (const float*)d_in[10];
    float* out = (float*)d_out;

    const size_t TEN = (size_t)B_DIM * C_DIM * N_DIM;   // 8,388,608 elems
    unsigned short* ws16  = (unsigned short*)d_ws;
    unsigned short* hT    = ws16;                    // [B][N][C] bf16
    unsigned short* qT    = hT    + TEN;             // [B][N][C] bf16
    unsigned short* kvbuf = qT    + TEN;             // [B][512][N] bf16 (k rows 0-255, v rows 256-511)
    unsigned short* kvb   = kvbuf + 2*TEN;           // [B][C][C] bf16
    unsigned short* M2b   = kvb   + 524288;          // [B][C][C] bf16
    unsigned short* wqb   = M2b   + 524288;
    unsigned short* wkvb  = wqb   + 65536;           // stacked [512][256]
    unsigned short* wob   = wkvb  + 131072;
    float*          bkv   = (float*)(wob + 65536);   // [512]
    float2*         sums  = (float2*)(bkv + 512);    // [B*C]
    float*          kvf   = (float*)(sums + 2048);   // [B][8][C*C] fp32 partials (16.8MB)

    // 1) prep: weights->bf16, bias concat, gn stats
    prep_kernel<<<dim3(2305), 256, 0, stream>>>(wq, wk, wv, wo, bk, bv, x,
                                                wqb, wkvb, wob, bkv, sums);
    // 2) groupnorm apply -> hT
    gn_apply<<<dim3(N_DIM/64, B_DIM), 256, 0, stream>>>(x, sums, gamma, beta, hT);
    // 3) fused qT + k/v GEMMs
    qkv_kernel<<<dim3(1536), 256, 0, stream>>>(hT, wqb, wkvb, bq, bkv, qT, kvbuf);
    // 4) kv[c][d] = sum_n k[c][n]*v[d][n]  M=256 N=256 K=4096, split-8 fp32
    gemm_nt<3><<<dim3(2, 2, B_DIM*8), 256, 0, stream>>>(
        kvbuf, kvbuf + 1048576, nullptr, nullptr, kvf,
        256, 4096, 8, 2097152, 2097152, 65536, 0, 1);
    // 5) reduce 8 partials -> kvb bf16
    kvred<<<dim3(512), 256, 0, stream>>>(kvf, kvb);
    // 6) M2[o][c] = sum_d wo[o][d]*kv[c][d]  M=256 N=256 K=256
    gemm_nt<4><<<dim3(2, 2, B_DIM), 256, 0, stream>>>(
        wob, kvb, nullptr, nullptr, M2b,
        256, 256, 1, 0, 65536, 65536, 0, 0);
    // 7) out[o][n] = sum_c M2[o][c]*qT[n][c] + bo[o] + x  M=256 N=4096 K=256
    gemm_nt<5><<<dim3(32, 2, B_DIM), 256, 0, stream>>>(
        M2b, qT, bo, x, out,
        4096, 256, 1, 65536, 1048576, 1048576, 1048576, 1);
}